// Round 1
// baseline (1052.671 us; speedup 1.0000x reference)
//
#include <hip/hip_runtime.h>
#include <math.h>

#define N_NODES 50000
#define N_EDGES 800000
#define N_GRAPHS 1024
#define DIM 64

// ---------------- degree / dinv ----------------

__global__ void zero_f32(float* __restrict__ p, int n) {
    int i = blockIdx.x * 256 + threadIdx.x;
    if (i < n) p[i] = 0.0f;
}

__global__ void deg_count(const int* __restrict__ col, float* __restrict__ deg) {
    int e = blockIdx.x * 256 + threadIdx.x;
    if (e < N_EDGES) atomicAdd(&deg[col[e]], 1.0f);
}

__global__ void make_dinv(float* __restrict__ deg_inplace) {
    int i = blockIdx.x * 256 + threadIdx.x;
    if (i < N_NODES) deg_inplace[i] = rsqrtf(deg_inplace[i] + 1.0f);  // +1 self-loop
}

// ---------------- per-layer kernels ----------------

// t[n][d] = sum_k h[n][k] * W[k][d]; hnext[n][d] = dinv[n]^2 * t[n][d] (self-loop msg)
template <int DIN>
__global__ void gemm_init(const float* __restrict__ h, const float* __restrict__ W,
                          const float* __restrict__ dinv,
                          float* __restrict__ t, float* __restrict__ hnext) {
    __shared__ float Wl[DIN * DIM];
    int tid = threadIdx.x;  // 256
    for (int i = tid; i < DIN * DIM; i += 256) Wl[i] = W[i];
    __syncthreads();
    int node = blockIdx.x * 4 + (tid >> 6);
    int d = tid & 63;
    if (node >= N_NODES) return;
    const float* hr = h + (size_t)node * DIN;
    float acc = 0.0f;
#pragma unroll
    for (int k = 0; k < DIN; ++k) acc += hr[k] * Wl[k * DIM + d];
    t[(size_t)node * DIM + d] = acc;
    float s = dinv[node];
    hnext[(size_t)node * DIM + d] = s * s * acc;
}

// one 64-lane group per edge; lane d handles dim d
__global__ void edge_scatter(const int* __restrict__ row, const int* __restrict__ col,
                             const float* __restrict__ dinv,
                             const float* __restrict__ t, float* __restrict__ hnext) {
    int e = blockIdx.x * 4 + (threadIdx.x >> 6);
    int d = threadIdx.x & 63;
    if (e >= N_EDGES) return;
    int r = row[e];
    int c = col[e];
    float nrm = dinv[r] * dinv[c];
    float v = nrm * t[(size_t)r * DIM + d];
    atomicAdd(&hnext[(size_t)c * DIM + d], v);
}

__global__ void tanh_bias(const float* __restrict__ hnext, const float* __restrict__ b,
                          float* __restrict__ hout) {
    int i = blockIdx.x * 256 + threadIdx.x;
    if (i < N_NODES * DIM) hout[i] = tanhf(hnext[i] + b[i & 63]);
}

// ---------------- pooling ----------------

__global__ void pool_init(unsigned* __restrict__ gkey, float* __restrict__ gsum,
                          float* __restrict__ gcnt) {
    int i = blockIdx.x * 256 + threadIdx.x;
    if (i < N_GRAPHS * DIM) { gkey[i] = 0u; gsum[i] = 0.0f; }
    if (i < N_GRAPHS) gcnt[i] = 0.0f;
}

__device__ __forceinline__ unsigned flip_key(float f) {
    unsigned u = __float_as_uint(f);
    return (u & 0x80000000u) ? ~u : (u | 0x80000000u);
}

__global__ void pool_scatter(const float* __restrict__ h, const int* __restrict__ batch,
                             unsigned* __restrict__ gkey, float* __restrict__ gsum,
                             float* __restrict__ gcnt) {
    int node = blockIdx.x * 4 + (threadIdx.x >> 6);
    int d = threadIdx.x & 63;
    if (node >= N_NODES) return;
    int g = batch[node];
    float v = h[(size_t)node * DIM + d];
    atomicMax(&gkey[g * DIM + d], flip_key(v));
    atomicAdd(&gsum[g * DIM + d], v);
    if (d == 0) atomicAdd(&gcnt[g], 1.0f);
}

__global__ void finalize(const unsigned* __restrict__ gkey, const float* __restrict__ gsum,
                         const float* __restrict__ gcnt, const float* __restrict__ Wout,
                         const float* __restrict__ bout, float* __restrict__ out) {
    int g = blockIdx.x * 4 + (threadIdx.x >> 6);
    int d = threadIdx.x & 63;
    if (g >= N_GRAPHS) return;
    unsigned key = gkey[g * DIM + d];
    unsigned u = (key & 0x80000000u) ? (key & 0x7fffffffu) : ~key;
    float mx = __uint_as_float(u);
    float mean = gsum[g * DIM + d] / fmaxf(gcnt[g], 1.0f);
    float v = mx * Wout[d] + mean * Wout[DIM + d];
#pragma unroll
    for (int off = 32; off > 0; off >>= 1) v += __shfl_down(v, off, 64);
    if (d == 0) out[g] = v + bout[0];
}

// ---------------- launch ----------------

static inline size_t align256(size_t x) { return (x + 255) & ~(size_t)255; }

extern "C" void kernel_launch(void* const* d_in, const int* in_sizes, int n_in,
                              void* d_out, int out_size, void* d_ws, size_t ws_size,
                              hipStream_t stream) {
    const float* x    = (const float*)d_in[0];
    const int*   ei   = (const int*)d_in[1];
    const int*   batch= (const int*)d_in[2];
    const float* W0   = (const float*)d_in[3];
    const float* b0   = (const float*)d_in[4];
    const float* W1   = (const float*)d_in[5];
    const float* b1   = (const float*)d_in[6];
    const float* W2   = (const float*)d_in[7];
    const float* b2   = (const float*)d_in[8];
    const float* W3   = (const float*)d_in[9];
    const float* b3   = (const float*)d_in[10];
    const float* Wout = (const float*)d_in[11];
    const float* bout = (const float*)d_in[12];
    float* out = (float*)d_out;

    const int* row = ei;            // edge_index[0] = source
    const int* col = ei + N_EDGES;  // edge_index[1] = destination

    char* ws = (char*)d_ws;
    size_t off = 0;
    float* dinv = (float*)(ws + off); off += align256((size_t)N_NODES * 4);
    float* t    = (float*)(ws + off); off += align256((size_t)N_NODES * DIM * 4);
    float* hA   = (float*)(ws + off); off += align256((size_t)N_NODES * DIM * 4);
    float* hC   = (float*)(ws + off); off += align256((size_t)N_NODES * DIM * 4);
    unsigned* gkey = (unsigned*)(ws + off); off += align256((size_t)N_GRAPHS * DIM * 4);
    float* gsum = (float*)(ws + off); off += align256((size_t)N_GRAPHS * DIM * 4);
    float* gcnt = (float*)(ws + off); off += align256((size_t)N_GRAPHS * 4);
    (void)ws_size;

    // degree -> dinv
    zero_f32<<<(N_NODES + 255) / 256, 256, 0, stream>>>(dinv, N_NODES);
    deg_count<<<(N_EDGES + 255) / 256, 256, 0, stream>>>(col, dinv);
    make_dinv<<<(N_NODES + 255) / 256, 256, 0, stream>>>(dinv);

    const int gemm_blocks = N_NODES / 4;        // 12500
    const int scat_blocks = N_EDGES / 4;        // 200000
    const int elem_blocks = N_NODES * DIM / 256; // 12500

    // layer 0 (D_IN = 9)
    gemm_init<9><<<gemm_blocks, 256, 0, stream>>>(x, W0, dinv, t, hC);
    edge_scatter<<<scat_blocks, 256, 0, stream>>>(row, col, dinv, t, hC);
    tanh_bias<<<elem_blocks, 256, 0, stream>>>(hC, b0, hA);

    const float* Ws[3] = {W1, W2, W3};
    const float* bs[3] = {b1, b2, b3};
    for (int l = 0; l < 3; ++l) {
        gemm_init<64><<<gemm_blocks, 256, 0, stream>>>(hA, Ws[l], dinv, t, hC);
        edge_scatter<<<scat_blocks, 256, 0, stream>>>(row, col, dinv, t, hC);
        tanh_bias<<<elem_blocks, 256, 0, stream>>>(hC, bs[l], hA);
    }

    // pooling
    pool_init<<<(N_GRAPHS * DIM + 255) / 256, 256, 0, stream>>>(gkey, gsum, gcnt);
    pool_scatter<<<gemm_blocks, 256, 0, stream>>>(hA, batch, gkey, gsum, gcnt);
    finalize<<<N_GRAPHS / 4, 256, 0, stream>>>(gkey, gsum, gcnt, Wout, bout, out);
    (void)out_size; (void)n_in; (void)in_sizes;
}

// Round 2
// 456.813 us; speedup vs baseline: 2.3044x; 2.3044x over previous
//
#include <hip/hip_runtime.h>
#include <math.h>

#define N_NODES 50000
#define N_EDGES 800000
#define N_GRAPHS 1024
#define DIM 64
#define SCAN_BLOCKS 196  // ceil(50000/256)

// ---------------- degree / CSR build ----------------

__global__ void zero_i32(int* __restrict__ p, int n) {
    int i = blockIdx.x * 256 + threadIdx.x;
    if (i < n) p[i] = 0;
}

__global__ void deg_count(const int* __restrict__ col, int* __restrict__ ideg) {
    int e = blockIdx.x * 256 + threadIdx.x;
    if (e < N_EDGES) atomicAdd(&ideg[col[e]], 1);
}

// exclusive scan, 256 elems per block
__global__ void scan_local(const int* __restrict__ ideg, int* __restrict__ rowtmp,
                           int* __restrict__ bsum) {
    __shared__ int s[256];
    int tid = threadIdx.x;
    int i = blockIdx.x * 256 + tid;
    int v = (i < N_NODES) ? ideg[i] : 0;
    s[tid] = v;
    __syncthreads();
    for (int off = 1; off < 256; off <<= 1) {
        int t2 = (tid >= off) ? s[tid - off] : 0;
        __syncthreads();
        s[tid] += t2;
        __syncthreads();
    }
    if (i < N_NODES) rowtmp[i] = s[tid] - v;  // exclusive
    if (tid == 255) bsum[blockIdx.x] = s[255];
}

__global__ void scan_block(const int* __restrict__ bsum, int* __restrict__ bsumoff) {
    __shared__ int s[256];
    int tid = threadIdx.x;
    int v = (tid < SCAN_BLOCKS) ? bsum[tid] : 0;
    s[tid] = v;
    __syncthreads();
    for (int off = 1; off < 256; off <<= 1) {
        int t2 = (tid >= off) ? s[tid - off] : 0;
        __syncthreads();
        s[tid] += t2;
        __syncthreads();
    }
    bsumoff[tid] = s[tid] - v;  // exclusive
}

__global__ void scan_final(const int* __restrict__ rowtmp, const int* __restrict__ bsumoff,
                           const int* __restrict__ ideg, int* __restrict__ rowptr,
                           int* __restrict__ cursor, float* __restrict__ dinv) {
    int i = blockIdx.x * 256 + threadIdx.x;
    if (i < N_NODES) {
        int r = rowtmp[i] + bsumoff[blockIdx.x];
        rowptr[i] = r;
        cursor[i] = r;
        dinv[i] = rsqrtf((float)ideg[i] + 1.0f);  // +1 self-loop
    }
    if (i == 0) rowptr[N_NODES] = N_EDGES;
}

__global__ void csr_fill(const int* __restrict__ row, const int* __restrict__ col,
                         const float* __restrict__ dinv, int* __restrict__ cursor,
                         int* __restrict__ esrc, float* __restrict__ enorm) {
    int e = blockIdx.x * 256 + threadIdx.x;
    if (e >= N_EDGES) return;
    int r = row[e];
    int c = col[e];
    int pos = atomicAdd(&cursor[c], 1);
    esrc[pos] = r;
    enorm[pos] = dinv[r] * dinv[c];
}

// ---------------- per-layer kernels ----------------

// t[n][d] = sum_k h[n][k] * W[k][d]
template <int DIN>
__global__ void gemm(const float* __restrict__ h, const float* __restrict__ W,
                     float* __restrict__ t) {
    __shared__ float Wl[DIN * DIM];
    int tid = threadIdx.x;  // 256
    for (int i = tid; i < DIN * DIM; i += 256) Wl[i] = W[i];
    __syncthreads();
    int node = blockIdx.x * 4 + (tid >> 6);
    int d = tid & 63;
    if (node >= N_NODES) return;
    const float* hr = h + (size_t)node * DIN;
    float acc = 0.0f;
#pragma unroll
    for (int k = 0; k < DIN; ++k) acc += hr[k] * Wl[k * DIM + d];
    t[(size_t)node * DIM + d] = acc;
}

// gather-aggregate per destination node + self loop + bias + tanh
__global__ void aggregate(const int* __restrict__ rowptr, const int* __restrict__ esrc,
                          const float* __restrict__ enorm, const float* __restrict__ dinv,
                          const float* __restrict__ t, const float* __restrict__ b,
                          float* __restrict__ hout) {
    int node = blockIdx.x * 4 + (threadIdx.x >> 6);
    int d = threadIdx.x & 63;
    if (node >= N_NODES) return;
    float s = dinv[node];
    float acc = s * s * t[(size_t)node * DIM + d];  // self-loop message
    int j = rowptr[node];
    int end = rowptr[node + 1];
    for (; j + 4 <= end; j += 4) {
        int r0 = esrc[j], r1 = esrc[j + 1], r2 = esrc[j + 2], r3 = esrc[j + 3];
        float n0 = enorm[j], n1 = enorm[j + 1], n2 = enorm[j + 2], n3 = enorm[j + 3];
        acc += n0 * t[(size_t)r0 * DIM + d];
        acc += n1 * t[(size_t)r1 * DIM + d];
        acc += n2 * t[(size_t)r2 * DIM + d];
        acc += n3 * t[(size_t)r3 * DIM + d];
    }
    for (; j < end; ++j) acc += enorm[j] * t[(size_t)esrc[j] * DIM + d];
    hout[(size_t)node * DIM + d] = tanhf(acc + b[d]);
}

// ---------------- pooling + output ----------------

__device__ __forceinline__ int lower_bound(const int* a, int n, int key) {
    int lo = 0, hi = n;
    while (lo < hi) {
        int mid = (lo + hi) >> 1;
        if (a[mid] < key) lo = mid + 1; else hi = mid;
    }
    return lo;
}

__global__ void pool_out(const float* __restrict__ h, const int* __restrict__ batch,
                         const float* __restrict__ Wout, const float* __restrict__ bout,
                         float* __restrict__ out) {
    __shared__ float smax[4][DIM];
    __shared__ float ssum[4][DIM];
    __shared__ int bounds[2];
    int g = blockIdx.x;
    int tid = threadIdx.x, w = tid >> 6, d = tid & 63;
    if (tid == 0) {
        bounds[0] = lower_bound(batch, N_NODES, g);
        bounds[1] = lower_bound(batch, N_NODES, g + 1);
    }
    __syncthreads();
    int start = bounds[0], end = bounds[1];
    float mx = -INFINITY, sum = 0.0f;
    for (int n = start + w; n < end; n += 4) {
        float v = h[(size_t)n * DIM + d];
        mx = fmaxf(mx, v);
        sum += v;
    }
    smax[w][d] = mx;
    ssum[w][d] = sum;
    __syncthreads();
    if (w == 0) {
        mx = fmaxf(fmaxf(smax[0][d], smax[1][d]), fmaxf(smax[2][d], smax[3][d]));
        sum = ssum[0][d] + ssum[1][d] + ssum[2][d] + ssum[3][d];
        float cnt = (float)(end - start);
        float mean = sum / fmaxf(cnt, 1.0f);
        float v = mx * Wout[d] + mean * Wout[DIM + d];
#pragma unroll
        for (int off = 32; off > 0; off >>= 1) v += __shfl_down(v, off, 64);
        if (d == 0) out[g] = v + bout[0];
    }
}

// ---------------- launch ----------------

static inline size_t align256(size_t x) { return (x + 255) & ~(size_t)255; }

extern "C" void kernel_launch(void* const* d_in, const int* in_sizes, int n_in,
                              void* d_out, int out_size, void* d_ws, size_t ws_size,
                              hipStream_t stream) {
    const float* x     = (const float*)d_in[0];
    const int*   ei    = (const int*)d_in[1];
    const int*   batch = (const int*)d_in[2];
    const float* W0    = (const float*)d_in[3];
    const float* b0    = (const float*)d_in[4];
    const float* W1    = (const float*)d_in[5];
    const float* b1    = (const float*)d_in[6];
    const float* W2    = (const float*)d_in[7];
    const float* b2    = (const float*)d_in[8];
    const float* W3    = (const float*)d_in[9];
    const float* b3    = (const float*)d_in[10];
    const float* Wout  = (const float*)d_in[11];
    const float* bout  = (const float*)d_in[12];
    float* out = (float*)d_out;

    const int* row = ei;            // source
    const int* col = ei + N_EDGES;  // destination

    char* ws = (char*)d_ws;
    size_t off = 0;
    int*   ideg    = (int*)(ws + off);   off += align256((size_t)N_NODES * 4);
    int*   rowtmp  = (int*)(ws + off);   off += align256((size_t)N_NODES * 4);
    int*   rowptr  = (int*)(ws + off);   off += align256(((size_t)N_NODES + 1) * 4);
    int*   cursor  = (int*)(ws + off);   off += align256((size_t)N_NODES * 4);
    int*   bsum    = (int*)(ws + off);   off += align256(256 * 4);
    int*   bsumoff = (int*)(ws + off);   off += align256(256 * 4);
    float* dinv    = (float*)(ws + off); off += align256((size_t)N_NODES * 4);
    int*   esrc    = (int*)(ws + off);   off += align256((size_t)N_EDGES * 4);
    float* enorm   = (float*)(ws + off); off += align256((size_t)N_EDGES * 4);
    float* t       = (float*)(ws + off); off += align256((size_t)N_NODES * DIM * 4);
    float* hA      = (float*)(ws + off); off += align256((size_t)N_NODES * DIM * 4);
    (void)ws_size;

    const int node_blocks = (N_NODES + 255) / 256;   // 196
    const int edge_blocks = (N_EDGES + 255) / 256;   // 3125
    const int wave_blocks = N_NODES / 4;             // 12500 (4 waves/block, 1 node/wave)

    // CSR build
    zero_i32<<<node_blocks, 256, 0, stream>>>(ideg, N_NODES);
    deg_count<<<edge_blocks, 256, 0, stream>>>(col, ideg);
    scan_local<<<SCAN_BLOCKS, 256, 0, stream>>>(ideg, rowtmp, bsum);
    scan_block<<<1, 256, 0, stream>>>(bsum, bsumoff);
    scan_final<<<SCAN_BLOCKS, 256, 0, stream>>>(rowtmp, bsumoff, ideg, rowptr, cursor, dinv);
    csr_fill<<<edge_blocks, 256, 0, stream>>>(row, col, dinv, cursor, esrc, enorm);

    // layer 0 (D_IN = 9)
    gemm<9><<<wave_blocks, 256, 0, stream>>>(x, W0, t);
    aggregate<<<wave_blocks, 256, 0, stream>>>(rowptr, esrc, enorm, dinv, t, b0, hA);

    const float* Ws[3] = {W1, W2, W3};
    const float* bs[3] = {b1, b2, b3};
    for (int l = 0; l < 3; ++l) {
        gemm<64><<<wave_blocks, 256, 0, stream>>>(hA, Ws[l], t);
        aggregate<<<wave_blocks, 256, 0, stream>>>(rowptr, esrc, enorm, dinv, t, bs[l], hA);
    }

    // pooling + output
    pool_out<<<N_GRAPHS, 256, 0, stream>>>(hA, batch, Wout, bout, out);
    (void)out_size; (void)n_in; (void)in_sizes;
}

// Round 3
// 407.656 us; speedup vs baseline: 2.5823x; 1.1206x over previous
//
#include <hip/hip_runtime.h>
#include <math.h>

#define N_NODES 50000
#define N_EDGES 800000
#define N_GRAPHS 1024
#define DIM 64
#define SCAN_BLOCKS 196  // ceil(50000/256)

// ---------------- degree / CSR build ----------------

__global__ void zero_i32(int* __restrict__ p, int n) {
    int i = blockIdx.x * 256 + threadIdx.x;
    if (i < n) p[i] = 0;
}

__global__ void deg_count(const int* __restrict__ col, int* __restrict__ ideg) {
    int e = blockIdx.x * 256 + threadIdx.x;
    if (e < N_EDGES) atomicAdd(&ideg[col[e]], 1);
}

// exclusive scan, 256 elems per block
__global__ void scan_local(const int* __restrict__ ideg, int* __restrict__ rowtmp,
                           int* __restrict__ bsum) {
    __shared__ int s[256];
    int tid = threadIdx.x;
    int i = blockIdx.x * 256 + tid;
    int v = (i < N_NODES) ? ideg[i] : 0;
    s[tid] = v;
    __syncthreads();
    for (int off = 1; off < 256; off <<= 1) {
        int t2 = (tid >= off) ? s[tid - off] : 0;
        __syncthreads();
        s[tid] += t2;
        __syncthreads();
    }
    if (i < N_NODES) rowtmp[i] = s[tid] - v;  // exclusive
    if (tid == 255) bsum[blockIdx.x] = s[255];
}

__global__ void scan_block(const int* __restrict__ bsum, int* __restrict__ bsumoff) {
    __shared__ int s[256];
    int tid = threadIdx.x;
    int v = (tid < SCAN_BLOCKS) ? bsum[tid] : 0;
    s[tid] = v;
    __syncthreads();
    for (int off = 1; off < 256; off <<= 1) {
        int t2 = (tid >= off) ? s[tid - off] : 0;
        __syncthreads();
        s[tid] += t2;
        __syncthreads();
    }
    bsumoff[tid] = s[tid] - v;  // exclusive
}

__global__ void scan_final(const int* __restrict__ rowtmp, const int* __restrict__ bsumoff,
                           const int* __restrict__ ideg, int* __restrict__ rowptr,
                           int* __restrict__ cursor, float* __restrict__ dinv) {
    int i = blockIdx.x * 256 + threadIdx.x;
    if (i < N_NODES) {
        int r = rowtmp[i] + bsumoff[blockIdx.x];
        rowptr[i] = r;
        cursor[i] = r;
        dinv[i] = rsqrtf((float)ideg[i] + 1.0f);  // +1 self-loop
    }
    if (i == 0) rowptr[N_NODES] = N_EDGES;
}

// packed (src, norm) -> single 8B scattered store per edge
__global__ void csr_fill(const int* __restrict__ row, const int* __restrict__ col,
                         const float* __restrict__ dinv, int* __restrict__ cursor,
                         int2* __restrict__ ecsr) {
    int e = blockIdx.x * 256 + threadIdx.x;
    if (e >= N_EDGES) return;
    int r = row[e];
    int c = col[e];
    int pos = atomicAdd(&cursor[c], 1);
    ecsr[pos] = make_int2(r, __float_as_int(dinv[r] * dinv[c]));
}

// ---------------- fused layer: aggregate(h) then transform ----------------
// out[n] = tanh( W^T (dinv[n]^2 h[n] + sum_e norm_e h[src_e]) + b )
// one 64-lane wave per node; lane d holds agg dim d (d < DIN) and computes out dim d.

template <int DIN>
__global__ void layer_fused(const int* __restrict__ rowptr, const int2* __restrict__ ecsr,
                            const float* __restrict__ dinv, const float* __restrict__ h,
                            const float* __restrict__ W, const float* __restrict__ b,
                            float* __restrict__ hout) {
    int tid = threadIdx.x;
    int node = blockIdx.x * 4 + (tid >> 6);  // grid = N_NODES/4 exactly
    int d = tid & 63;

    // W column d in registers: wcol[k] = W[k][d]
    float wcol[DIN];
#pragma unroll
    for (int k = 0; k < DIN; ++k) wcol[k] = W[k * DIM + d];

    float s = dinv[node];
    float agg = 0.0f;
    if (d < DIN) agg = s * s * h[(size_t)node * DIN + d];  // self-loop

    int j = rowptr[node];
    int end = rowptr[node + 1];
    for (; j + 4 <= end; j += 4) {
        int2 e0 = ecsr[j], e1 = ecsr[j + 1], e2 = ecsr[j + 2], e3 = ecsr[j + 3];
        if (d < DIN) {
            agg += __int_as_float(e0.y) * h[(size_t)e0.x * DIN + d];
            agg += __int_as_float(e1.y) * h[(size_t)e1.x * DIN + d];
            agg += __int_as_float(e2.y) * h[(size_t)e2.x * DIN + d];
            agg += __int_as_float(e3.y) * h[(size_t)e3.x * DIN + d];
        }
    }
    for (; j < end; ++j) {
        int2 e = ecsr[j];
        if (d < DIN) agg += __int_as_float(e.y) * h[(size_t)e.x * DIN + d];
    }

    // in-register GEMM: acc_d = sum_k agg_k * W[k][d], agg_k broadcast via readlane
    float acc[4] = {0.0f, 0.0f, 0.0f, 0.0f};
#pragma unroll
    for (int k = 0; k < DIN; ++k) acc[k & 3] += __shfl(agg, k, 64) * wcol[k];
    float r = (acc[0] + acc[1]) + (acc[2] + acc[3]);
    hout[(size_t)node * DIM + d] = tanhf(r + b[d]);
}

// ---------------- pooling + output ----------------

__device__ __forceinline__ int lower_bound(const int* a, int n, int key) {
    int lo = 0, hi = n;
    while (lo < hi) {
        int mid = (lo + hi) >> 1;
        if (a[mid] < key) lo = mid + 1; else hi = mid;
    }
    return lo;
}

__global__ void pool_out(const float* __restrict__ h, const int* __restrict__ batch,
                         const float* __restrict__ Wout, const float* __restrict__ bout,
                         float* __restrict__ out) {
    __shared__ float smax[4][DIM];
    __shared__ float ssum[4][DIM];
    __shared__ int bounds[2];
    int g = blockIdx.x;
    int tid = threadIdx.x, w = tid >> 6, d = tid & 63;
    if (tid == 0) {
        bounds[0] = lower_bound(batch, N_NODES, g);
        bounds[1] = lower_bound(batch, N_NODES, g + 1);
    }
    __syncthreads();
    int start = bounds[0], end = bounds[1];
    float mx = -INFINITY, sum = 0.0f;
    for (int n = start + w; n < end; n += 4) {
        float v = h[(size_t)n * DIM + d];
        mx = fmaxf(mx, v);
        sum += v;
    }
    smax[w][d] = mx;
    ssum[w][d] = sum;
    __syncthreads();
    if (w == 0) {
        mx = fmaxf(fmaxf(smax[0][d], smax[1][d]), fmaxf(smax[2][d], smax[3][d]));
        sum = ssum[0][d] + ssum[1][d] + ssum[2][d] + ssum[3][d];
        float cnt = (float)(end - start);
        float mean = sum / fmaxf(cnt, 1.0f);
        float v = mx * Wout[d] + mean * Wout[DIM + d];
#pragma unroll
        for (int off = 32; off > 0; off >>= 1) v += __shfl_down(v, off, 64);
        if (d == 0) out[g] = v + bout[0];
    }
}

// ---------------- launch ----------------

static inline size_t align256(size_t x) { return (x + 255) & ~(size_t)255; }

extern "C" void kernel_launch(void* const* d_in, const int* in_sizes, int n_in,
                              void* d_out, int out_size, void* d_ws, size_t ws_size,
                              hipStream_t stream) {
    const float* x     = (const float*)d_in[0];
    const int*   ei    = (const int*)d_in[1];
    const int*   batch = (const int*)d_in[2];
    const float* W0    = (const float*)d_in[3];
    const float* b0    = (const float*)d_in[4];
    const float* W1    = (const float*)d_in[5];
    const float* b1    = (const float*)d_in[6];
    const float* W2    = (const float*)d_in[7];
    const float* b2    = (const float*)d_in[8];
    const float* W3    = (const float*)d_in[9];
    const float* b3    = (const float*)d_in[10];
    const float* Wout  = (const float*)d_in[11];
    const float* bout  = (const float*)d_in[12];
    float* out = (float*)d_out;

    const int* row = ei;            // source
    const int* col = ei + N_EDGES;  // destination

    char* ws = (char*)d_ws;
    size_t off = 0;
    int*   ideg    = (int*)(ws + off);   off += align256((size_t)N_NODES * 4);
    int*   rowtmp  = (int*)(ws + off);   off += align256((size_t)N_NODES * 4);
    int*   rowptr  = (int*)(ws + off);   off += align256(((size_t)N_NODES + 1) * 4);
    int*   cursor  = (int*)(ws + off);   off += align256((size_t)N_NODES * 4);
    int*   bsum    = (int*)(ws + off);   off += align256(256 * 4);
    int*   bsumoff = (int*)(ws + off);   off += align256(256 * 4);
    float* dinv    = (float*)(ws + off); off += align256((size_t)N_NODES * 4);
    int2*  ecsr    = (int2*)(ws + off);  off += align256((size_t)N_EDGES * 8);
    float* hA      = (float*)(ws + off); off += align256((size_t)N_NODES * DIM * 4);
    float* hB      = (float*)(ws + off); off += align256((size_t)N_NODES * DIM * 4);
    (void)ws_size;

    const int node_blocks = (N_NODES + 255) / 256;   // 196
    const int edge_blocks = (N_EDGES + 255) / 256;   // 3125
    const int wave_blocks = N_NODES / 4;             // 12500 (4 waves/block, 1 node/wave)

    // CSR build
    zero_i32<<<node_blocks, 256, 0, stream>>>(ideg, N_NODES);
    deg_count<<<edge_blocks, 256, 0, stream>>>(col, ideg);
    scan_local<<<SCAN_BLOCKS, 256, 0, stream>>>(ideg, rowtmp, bsum);
    scan_block<<<1, 256, 0, stream>>>(bsum, bsumoff);
    scan_final<<<SCAN_BLOCKS, 256, 0, stream>>>(rowtmp, bsumoff, ideg, rowptr, cursor, dinv);
    csr_fill<<<edge_blocks, 256, 0, stream>>>(row, col, dinv, cursor, ecsr);

    // fused layers: aggregate(h) -> GEMM -> bias -> tanh
    layer_fused<9><<<wave_blocks, 256, 0, stream>>>(rowptr, ecsr, dinv, x, W0, b0, hA);
    layer_fused<64><<<wave_blocks, 256, 0, stream>>>(rowptr, ecsr, dinv, hA, W1, b1, hB);
    layer_fused<64><<<wave_blocks, 256, 0, stream>>>(rowptr, ecsr, dinv, hB, W2, b2, hA);
    layer_fused<64><<<wave_blocks, 256, 0, stream>>>(rowptr, ecsr, dinv, hA, W3, b3, hB);

    // pooling + output
    pool_out<<<N_GRAPHS, 256, 0, stream>>>(hB, batch, Wout, bout, out);
    (void)out_size; (void)n_in; (void)in_sizes;
}

// Round 4
// 347.898 us; speedup vs baseline: 3.0258x; 1.1718x over previous
//
#include <hip/hip_runtime.h>
#include <math.h>

#define N_NODES 50000
#define N_EDGES 800000
#define N_GRAPHS 1024
#define DIM 64
#define SCAN_BLOCKS 196  // ceil(50000/256)

// ---------------- degree / CSR build ----------------

__global__ void zero_i32(int* __restrict__ p, int n) {
    int i = blockIdx.x * 256 + threadIdx.x;
    if (i < n) p[i] = 0;
}

__global__ void deg_count(const int* __restrict__ col, int* __restrict__ ideg) {
    int e = blockIdx.x * 256 + threadIdx.x;
    if (e < N_EDGES) atomicAdd(&ideg[col[e]], 1);
}

// exclusive scan, 256 elems per block
__global__ void scan_local(const int* __restrict__ ideg, int* __restrict__ rowtmp,
                           int* __restrict__ bsum) {
    __shared__ int s[256];
    int tid = threadIdx.x;
    int i = blockIdx.x * 256 + tid;
    int v = (i < N_NODES) ? ideg[i] : 0;
    s[tid] = v;
    __syncthreads();
    for (int off = 1; off < 256; off <<= 1) {
        int t2 = (tid >= off) ? s[tid - off] : 0;
        __syncthreads();
        s[tid] += t2;
        __syncthreads();
    }
    if (i < N_NODES) rowtmp[i] = s[tid] - v;  // exclusive
    if (tid == 255) bsum[blockIdx.x] = s[255];
}

__global__ void scan_block(const int* __restrict__ bsum, int* __restrict__ bsumoff) {
    __shared__ int s[256];
    int tid = threadIdx.x;
    int v = (tid < SCAN_BLOCKS) ? bsum[tid] : 0;
    s[tid] = v;
    __syncthreads();
    for (int off = 1; off < 256; off <<= 1) {
        int t2 = (tid >= off) ? s[tid - off] : 0;
        __syncthreads();
        s[tid] += t2;
        __syncthreads();
    }
    bsumoff[tid] = s[tid] - v;  // exclusive
}

__global__ void scan_final(const int* __restrict__ rowtmp, const int* __restrict__ bsumoff,
                           const int* __restrict__ ideg, int* __restrict__ rowptr,
                           int* __restrict__ cursor, float* __restrict__ dinv) {
    int i = blockIdx.x * 256 + threadIdx.x;
    if (i < N_NODES) {
        int r = rowtmp[i] + bsumoff[blockIdx.x];
        rowptr[i] = r;
        cursor[i] = r;
        dinv[i] = rsqrtf((float)ideg[i] + 1.0f);  // +1 self-loop
    }
    if (i == 0) rowptr[N_NODES] = N_EDGES;
}

// packed (src, norm) -> single 8B scattered store per edge
__global__ void csr_fill(const int* __restrict__ row, const int* __restrict__ col,
                         const float* __restrict__ dinv, int* __restrict__ cursor,
                         int2* __restrict__ ecsr) {
    int e = blockIdx.x * 256 + threadIdx.x;
    if (e >= N_EDGES) return;
    int r = row[e];
    int c = col[e];
    int pos = atomicAdd(&cursor[c], 1);
    ecsr[pos] = make_int2(r, __float_as_int(dinv[r] * dinv[c]));
}

// ---------------- fused layer, DIN=64 ----------------
// wave = 4 groups x 16 lanes; group g handles edges start+g, start+g+4, ...
// lane loads float4 chunk `sub` of the source row -> 16 row-gathers in flight.

__global__ void layer64_fused(const int* __restrict__ rowptr, const int2* __restrict__ ecsr,
                              const float* __restrict__ dinv, const float4* __restrict__ h4,
                              const float* __restrict__ W, const float* __restrict__ b,
                              float* __restrict__ hout) {
    int tid = threadIdx.x;
    int node = blockIdx.x * 4 + (tid >> 6);  // grid = N_NODES/4 exactly
    int lane = tid & 63;
    int sub = lane & 15;   // float4 chunk: dims [4*sub, 4*sub+4)
    int grp = lane >> 4;   // 0..3

    float4 acc = make_float4(0.0f, 0.0f, 0.0f, 0.0f);
    int start = rowptr[node];
    int end = rowptr[node + 1];

    if (grp == 0) {  // self-loop message, counted once
        float s = dinv[node];
        float s2 = s * s;
        float4 hv = h4[(size_t)node * 16 + sub];
        acc.x = s2 * hv.x; acc.y = s2 * hv.y; acc.z = s2 * hv.z; acc.w = s2 * hv.w;
    }

    int j = start + grp;
    // 4 edges per group per iteration -> 16 gathers in flight per wave
    for (; j + 12 < end; j += 16) {
        int2 e0 = ecsr[j], e1 = ecsr[j + 4], e2 = ecsr[j + 8], e3 = ecsr[j + 12];
        float4 r0 = h4[(size_t)e0.x * 16 + sub];
        float4 r1 = h4[(size_t)e1.x * 16 + sub];
        float4 r2 = h4[(size_t)e2.x * 16 + sub];
        float4 r3 = h4[(size_t)e3.x * 16 + sub];
        float n0 = __int_as_float(e0.y), n1 = __int_as_float(e1.y);
        float n2 = __int_as_float(e2.y), n3 = __int_as_float(e3.y);
        acc.x += n0 * r0.x; acc.y += n0 * r0.y; acc.z += n0 * r0.z; acc.w += n0 * r0.w;
        acc.x += n1 * r1.x; acc.y += n1 * r1.y; acc.z += n1 * r1.z; acc.w += n1 * r1.w;
        acc.x += n2 * r2.x; acc.y += n2 * r2.y; acc.z += n2 * r2.z; acc.w += n2 * r2.w;
        acc.x += n3 * r3.x; acc.y += n3 * r3.y; acc.z += n3 * r3.z; acc.w += n3 * r3.w;
    }
    for (; j < end; j += 4) {
        int2 e = ecsr[j];
        float4 r = h4[(size_t)e.x * 16 + sub];
        float n = __int_as_float(e.y);
        acc.x += n * r.x; acc.y += n * r.y; acc.z += n * r.z; acc.w += n * r.w;
    }

    // fold the 4 group partials; afterwards every lane holds agg[4*sub .. 4*sub+3]
    acc.x += __shfl_xor(acc.x, 16, 64); acc.y += __shfl_xor(acc.y, 16, 64);
    acc.z += __shfl_xor(acc.z, 16, 64); acc.w += __shfl_xor(acc.w, 16, 64);
    acc.x += __shfl_xor(acc.x, 32, 64); acc.y += __shfl_xor(acc.y, 32, 64);
    acc.z += __shfl_xor(acc.z, 32, 64); acc.w += __shfl_xor(acc.w, 32, 64);

    // in-register GEMM: out[lane] = sum_k agg[k] * W[k][lane]; agg[4q+c] lives in lane q
    float o0 = 0.0f, o1 = 0.0f, o2 = 0.0f, o3 = 0.0f;
#pragma unroll
    for (int q = 0; q < 16; ++q) {
        float a0 = __shfl(acc.x, q, 64);
        float a1 = __shfl(acc.y, q, 64);
        float a2 = __shfl(acc.z, q, 64);
        float a3 = __shfl(acc.w, q, 64);
        o0 += a0 * W[(4 * q + 0) * DIM + lane];
        o1 += a1 * W[(4 * q + 1) * DIM + lane];
        o2 += a2 * W[(4 * q + 2) * DIM + lane];
        o3 += a3 * W[(4 * q + 3) * DIM + lane];
    }
    float r = (o0 + o1) + (o2 + o3);
    hout[(size_t)node * DIM + lane] = tanhf(r + b[lane]);
}

// ---------------- fused layer 0, DIN=9 (scalar chunks) ----------------

__global__ void layer0_fused(const int* __restrict__ rowptr, const int2* __restrict__ ecsr,
                             const float* __restrict__ dinv, const float* __restrict__ x,
                             const float* __restrict__ W, const float* __restrict__ b,
                             float* __restrict__ hout) {
    const int DIN = 9;
    int tid = threadIdx.x;
    int node = blockIdx.x * 4 + (tid >> 6);
    int lane = tid & 63;
    int sub = lane & 15;
    int grp = lane >> 4;
    bool act = sub < DIN;

    float acc = 0.0f;
    int start = rowptr[node];
    int end = rowptr[node + 1];

    if (grp == 0 && act) {
        float s = dinv[node];
        acc = s * s * x[(size_t)node * DIN + sub];
    }

    int j = start + grp;
    for (; j + 12 < end; j += 16) {
        int2 e0 = ecsr[j], e1 = ecsr[j + 4], e2 = ecsr[j + 8], e3 = ecsr[j + 12];
        if (act) {
            acc += __int_as_float(e0.y) * x[(size_t)e0.x * DIN + sub];
            acc += __int_as_float(e1.y) * x[(size_t)e1.x * DIN + sub];
            acc += __int_as_float(e2.y) * x[(size_t)e2.x * DIN + sub];
            acc += __int_as_float(e3.y) * x[(size_t)e3.x * DIN + sub];
        }
    }
    for (; j < end; j += 4) {
        int2 e = ecsr[j];
        if (act) acc += __int_as_float(e.y) * x[(size_t)e.x * DIN + sub];
    }

    acc += __shfl_xor(acc, 16, 64);
    acc += __shfl_xor(acc, 32, 64);

    float o = 0.0f;
#pragma unroll
    for (int k = 0; k < DIN; ++k) o += __shfl(acc, k, 64) * W[k * DIM + lane];
    hout[(size_t)node * DIM + lane] = tanhf(o + b[lane]);
}

// ---------------- pooling + output ----------------

__device__ __forceinline__ int lower_bound(const int* a, int n, int key) {
    int lo = 0, hi = n;
    while (lo < hi) {
        int mid = (lo + hi) >> 1;
        if (a[mid] < key) lo = mid + 1; else hi = mid;
    }
    return lo;
}

__global__ void pool_out(const float* __restrict__ h, const int* __restrict__ batch,
                         const float* __restrict__ Wout, const float* __restrict__ bout,
                         float* __restrict__ out) {
    __shared__ float smax[4][DIM];
    __shared__ float ssum[4][DIM];
    __shared__ int bounds[2];
    int g = blockIdx.x;
    int tid = threadIdx.x, w = tid >> 6, d = tid & 63;
    if (tid == 0) {
        bounds[0] = lower_bound(batch, N_NODES, g);
        bounds[1] = lower_bound(batch, N_NODES, g + 1);
    }
    __syncthreads();
    int start = bounds[0], end = bounds[1];
    float mx = -INFINITY, sum = 0.0f;
    for (int n = start + w; n < end; n += 4) {
        float v = h[(size_t)n * DIM + d];
        mx = fmaxf(mx, v);
        sum += v;
    }
    smax[w][d] = mx;
    ssum[w][d] = sum;
    __syncthreads();
    if (w == 0) {
        mx = fmaxf(fmaxf(smax[0][d], smax[1][d]), fmaxf(smax[2][d], smax[3][d]));
        sum = ssum[0][d] + ssum[1][d] + ssum[2][d] + ssum[3][d];
        float cnt = (float)(end - start);
        float mean = sum / fmaxf(cnt, 1.0f);
        float v = mx * Wout[d] + mean * Wout[DIM + d];
#pragma unroll
        for (int off = 32; off > 0; off >>= 1) v += __shfl_down(v, off, 64);
        if (d == 0) out[g] = v + bout[0];
    }
}

// ---------------- launch ----------------

static inline size_t align256(size_t x) { return (x + 255) & ~(size_t)255; }

extern "C" void kernel_launch(void* const* d_in, const int* in_sizes, int n_in,
                              void* d_out, int out_size, void* d_ws, size_t ws_size,
                              hipStream_t stream) {
    const float* x     = (const float*)d_in[0];
    const int*   ei    = (const int*)d_in[1];
    const int*   batch = (const int*)d_in[2];
    const float* W0    = (const float*)d_in[3];
    const float* b0    = (const float*)d_in[4];
    const float* W1    = (const float*)d_in[5];
    const float* b1    = (const float*)d_in[6];
    const float* W2    = (const float*)d_in[7];
    const float* b2    = (const float*)d_in[8];
    const float* W3    = (const float*)d_in[9];
    const float* b3    = (const float*)d_in[10];
    const float* Wout  = (const float*)d_in[11];
    const float* bout  = (const float*)d_in[12];
    float* out = (float*)d_out;

    const int* row = ei;            // source
    const int* col = ei + N_EDGES;  // destination

    char* ws = (char*)d_ws;
    size_t off = 0;
    int*   ideg    = (int*)(ws + off);   off += align256((size_t)N_NODES * 4);
    int*   rowtmp  = (int*)(ws + off);   off += align256((size_t)N_NODES * 4);
    int*   rowptr  = (int*)(ws + off);   off += align256(((size_t)N_NODES + 1) * 4);
    int*   cursor  = (int*)(ws + off);   off += align256((size_t)N_NODES * 4);
    int*   bsum    = (int*)(ws + off);   off += align256(256 * 4);
    int*   bsumoff = (int*)(ws + off);   off += align256(256 * 4);
    float* dinv    = (float*)(ws + off); off += align256((size_t)N_NODES * 4);
    int2*  ecsr    = (int2*)(ws + off);  off += align256((size_t)N_EDGES * 8);
    float* hA      = (float*)(ws + off); off += align256((size_t)N_NODES * DIM * 4);
    float* hB      = (float*)(ws + off); off += align256((size_t)N_NODES * DIM * 4);
    (void)ws_size;

    const int node_blocks = (N_NODES + 255) / 256;   // 196
    const int edge_blocks = (N_EDGES + 255) / 256;   // 3125
    const int wave_blocks = N_NODES / 4;             // 12500 (4 waves/block, 1 node/wave)

    // CSR build
    zero_i32<<<node_blocks, 256, 0, stream>>>(ideg, N_NODES);
    deg_count<<<edge_blocks, 256, 0, stream>>>(col, ideg);
    scan_local<<<SCAN_BLOCKS, 256, 0, stream>>>(ideg, rowtmp, bsum);
    scan_block<<<1, 256, 0, stream>>>(bsum, bsumoff);
    scan_final<<<SCAN_BLOCKS, 256, 0, stream>>>(rowtmp, bsumoff, ideg, rowptr, cursor, dinv);
    csr_fill<<<edge_blocks, 256, 0, stream>>>(row, col, dinv, cursor, ecsr);

    // fused layers
    layer0_fused<<<wave_blocks, 256, 0, stream>>>(rowptr, ecsr, dinv, x, W0, b0, hA);
    layer64_fused<<<wave_blocks, 256, 0, stream>>>(rowptr, ecsr, dinv, (const float4*)hA, W1, b1, hB);
    layer64_fused<<<wave_blocks, 256, 0, stream>>>(rowptr, ecsr, dinv, (const float4*)hB, W2, b2, hA);
    layer64_fused<<<wave_blocks, 256, 0, stream>>>(rowptr, ecsr, dinv, (const float4*)hA, W3, b3, hB);

    // pooling + output
    pool_out<<<N_GRAPHS, 256, 0, stream>>>(hB, batch, Wout, bout, out);
    (void)out_size; (void)n_in; (void)in_sizes;
}

// Round 5
// 336.865 us; speedup vs baseline: 3.1249x; 1.0328x over previous
//
#include <hip/hip_runtime.h>
#include <hip/hip_fp16.h>
#include <math.h>

#define N_NODES 50000
#define N_EDGES 800000
#define N_GRAPHS 1024
#define DIM 64
#define SCAN_BLOCKS 196  // ceil(50000/256)

// ---------------- degree / CSR build ----------------

__global__ void zero_i32(int* __restrict__ p, int n) {
    int i = blockIdx.x * 256 + threadIdx.x;
    if (i < n) p[i] = 0;
}

__global__ void deg_count(const int* __restrict__ col, int* __restrict__ ideg) {
    int e = blockIdx.x * 256 + threadIdx.x;
    if (e < N_EDGES) atomicAdd(&ideg[col[e]], 1);
}

// exclusive scan, 256 elems per block
__global__ void scan_local(const int* __restrict__ ideg, int* __restrict__ rowtmp,
                           int* __restrict__ bsum) {
    __shared__ int s[256];
    int tid = threadIdx.x;
    int i = blockIdx.x * 256 + tid;
    int v = (i < N_NODES) ? ideg[i] : 0;
    s[tid] = v;
    __syncthreads();
    for (int off = 1; off < 256; off <<= 1) {
        int t2 = (tid >= off) ? s[tid - off] : 0;
        __syncthreads();
        s[tid] += t2;
        __syncthreads();
    }
    if (i < N_NODES) rowtmp[i] = s[tid] - v;  // exclusive
    if (tid == 255) bsum[blockIdx.x] = s[255];
}

__global__ void scan_block(const int* __restrict__ bsum, int* __restrict__ bsumoff) {
    __shared__ int s[256];
    int tid = threadIdx.x;
    int v = (tid < SCAN_BLOCKS) ? bsum[tid] : 0;
    s[tid] = v;
    __syncthreads();
    for (int off = 1; off < 256; off <<= 1) {
        int t2 = (tid >= off) ? s[tid - off] : 0;
        __syncthreads();
        s[tid] += t2;
        __syncthreads();
    }
    bsumoff[tid] = s[tid] - v;  // exclusive
}

__global__ void scan_final(const int* __restrict__ rowtmp, const int* __restrict__ bsumoff,
                           const int* __restrict__ ideg, int* __restrict__ rowptr,
                           int* __restrict__ cursor, float* __restrict__ dinv) {
    int i = blockIdx.x * 256 + threadIdx.x;
    if (i < N_NODES) {
        int r = rowtmp[i] + bsumoff[blockIdx.x];
        rowptr[i] = r;
        cursor[i] = r;
        dinv[i] = rsqrtf((float)ideg[i] + 1.0f);  // +1 self-loop
    }
    if (i == 0) rowptr[N_NODES] = N_EDGES;
}

// packed (src, norm) -> single 8B scattered store per edge
__global__ void csr_fill(const int* __restrict__ row, const int* __restrict__ col,
                         const float* __restrict__ dinv, int* __restrict__ cursor,
                         int2* __restrict__ ecsr) {
    int e = blockIdx.x * 256 + threadIdx.x;
    if (e >= N_EDGES) return;
    int r = row[e];
    int c = col[e];
    int pos = atomicAdd(&cursor[c], 1);
    ecsr[pos] = make_int2(r, __float_as_int(dinv[r] * dinv[c]));
}

// ---------------- helpers ----------------

__device__ __forceinline__ float4 ld_h4(const uint2* __restrict__ h2, size_t node, int sub) {
    uint2 v = h2[node * 16 + sub];
    __half2 a = *reinterpret_cast<const __half2*>(&v.x);
    __half2 b = *reinterpret_cast<const __half2*>(&v.y);
    float2 fa = __half22float2(a);
    float2 fb = __half22float2(b);
    return make_float4(fa.x, fa.y, fb.x, fb.y);
}

__device__ __forceinline__ void st_out(float* __restrict__ p, size_t i, float v) { p[i] = v; }
__device__ __forceinline__ void st_out(__half* __restrict__ p, size_t i, float v) {
    p[i] = __float2half(v);
}

// ---------------- fused layer, DIN=64, fp16 gather buffer ----------------
// wave = 4 groups x 16 lanes; group g handles edges start+g, start+g+4, ...
// lane loads 8 B (4 halves) of the source row -> 16 row-gathers in flight.

template <typename OUT>
__global__ void layer64h(const int* __restrict__ rowptr, const int2* __restrict__ ecsr,
                         const float* __restrict__ dinv, const uint2* __restrict__ h2,
                         const float* __restrict__ W, const float* __restrict__ b,
                         OUT* __restrict__ hout) {
    int tid = threadIdx.x;
    int node = blockIdx.x * 4 + (tid >> 6);  // grid = N_NODES/4 exactly
    int lane = tid & 63;
    int sub = lane & 15;   // half4 chunk: dims [4*sub, 4*sub+4)
    int grp = lane >> 4;   // 0..3

    float4 acc = make_float4(0.0f, 0.0f, 0.0f, 0.0f);
    int start = rowptr[node];
    int end = rowptr[node + 1];

    if (grp == 0) {  // self-loop message, counted once
        float s = dinv[node];
        float s2 = s * s;
        float4 hv = ld_h4(h2, (size_t)node, sub);
        acc.x = s2 * hv.x; acc.y = s2 * hv.y; acc.z = s2 * hv.z; acc.w = s2 * hv.w;
    }

    int j = start + grp;
    for (; j + 12 < end; j += 16) {
        int2 e0 = ecsr[j], e1 = ecsr[j + 4], e2 = ecsr[j + 8], e3 = ecsr[j + 12];
        float4 r0 = ld_h4(h2, (size_t)e0.x, sub);
        float4 r1 = ld_h4(h2, (size_t)e1.x, sub);
        float4 r2 = ld_h4(h2, (size_t)e2.x, sub);
        float4 r3 = ld_h4(h2, (size_t)e3.x, sub);
        float n0 = __int_as_float(e0.y), n1 = __int_as_float(e1.y);
        float n2 = __int_as_float(e2.y), n3 = __int_as_float(e3.y);
        acc.x += n0 * r0.x; acc.y += n0 * r0.y; acc.z += n0 * r0.z; acc.w += n0 * r0.w;
        acc.x += n1 * r1.x; acc.y += n1 * r1.y; acc.z += n1 * r1.z; acc.w += n1 * r1.w;
        acc.x += n2 * r2.x; acc.y += n2 * r2.y; acc.z += n2 * r2.z; acc.w += n2 * r2.w;
        acc.x += n3 * r3.x; acc.y += n3 * r3.y; acc.z += n3 * r3.z; acc.w += n3 * r3.w;
    }
    for (; j < end; j += 4) {
        int2 e = ecsr[j];
        float4 r = ld_h4(h2, (size_t)e.x, sub);
        float n = __int_as_float(e.y);
        acc.x += n * r.x; acc.y += n * r.y; acc.z += n * r.z; acc.w += n * r.w;
    }

    // fold the 4 group partials; afterwards every lane holds agg[4*sub .. 4*sub+3]
    acc.x += __shfl_xor(acc.x, 16, 64); acc.y += __shfl_xor(acc.y, 16, 64);
    acc.z += __shfl_xor(acc.z, 16, 64); acc.w += __shfl_xor(acc.w, 16, 64);
    acc.x += __shfl_xor(acc.x, 32, 64); acc.y += __shfl_xor(acc.y, 32, 64);
    acc.z += __shfl_xor(acc.z, 32, 64); acc.w += __shfl_xor(acc.w, 32, 64);

    // in-register GEMM: out[lane] = sum_k agg[k] * W[k][lane]; agg[4q+c] lives in lane q
    float o0 = 0.0f, o1 = 0.0f, o2 = 0.0f, o3 = 0.0f;
#pragma unroll
    for (int q = 0; q < 16; ++q) {
        float a0 = __shfl(acc.x, q, 64);
        float a1 = __shfl(acc.y, q, 64);
        float a2 = __shfl(acc.z, q, 64);
        float a3 = __shfl(acc.w, q, 64);
        o0 += a0 * W[(4 * q + 0) * DIM + lane];
        o1 += a1 * W[(4 * q + 1) * DIM + lane];
        o2 += a2 * W[(4 * q + 2) * DIM + lane];
        o3 += a3 * W[(4 * q + 3) * DIM + lane];
    }
    float r = (o0 + o1) + (o2 + o3);
    st_out(hout, (size_t)node * DIM + lane, tanhf(r + b[lane]));
}

// ---------------- fused layer 0, DIN=9 (f32 x input, fp16 out) ----------------

__global__ void layer0_fused(const int* __restrict__ rowptr, const int2* __restrict__ ecsr,
                             const float* __restrict__ dinv, const float* __restrict__ x,
                             const float* __restrict__ W, const float* __restrict__ b,
                             __half* __restrict__ hout) {
    const int DIN = 9;
    int tid = threadIdx.x;
    int node = blockIdx.x * 4 + (tid >> 6);
    int lane = tid & 63;
    int sub = lane & 15;
    int grp = lane >> 4;
    bool act = sub < DIN;

    float acc = 0.0f;
    int start = rowptr[node];
    int end = rowptr[node + 1];

    if (grp == 0 && act) {
        float s = dinv[node];
        acc = s * s * x[(size_t)node * DIN + sub];
    }

    int j = start + grp;
    for (; j + 12 < end; j += 16) {
        int2 e0 = ecsr[j], e1 = ecsr[j + 4], e2 = ecsr[j + 8], e3 = ecsr[j + 12];
        if (act) {
            acc += __int_as_float(e0.y) * x[(size_t)e0.x * DIN + sub];
            acc += __int_as_float(e1.y) * x[(size_t)e1.x * DIN + sub];
            acc += __int_as_float(e2.y) * x[(size_t)e2.x * DIN + sub];
            acc += __int_as_float(e3.y) * x[(size_t)e3.x * DIN + sub];
        }
    }
    for (; j < end; j += 4) {
        int2 e = ecsr[j];
        if (act) acc += __int_as_float(e.y) * x[(size_t)e.x * DIN + sub];
    }

    acc += __shfl_xor(acc, 16, 64);
    acc += __shfl_xor(acc, 32, 64);

    float o = 0.0f;
#pragma unroll
    for (int k = 0; k < DIN; ++k) o += __shfl(acc, k, 64) * W[k * DIM + lane];
    hout[(size_t)node * DIM + lane] = __float2half(tanhf(o + b[lane]));
}

// ---------------- pooling + output ----------------

__device__ __forceinline__ int lower_bound(const int* a, int n, int key) {
    int lo = 0, hi = n;
    while (lo < hi) {
        int mid = (lo + hi) >> 1;
        if (a[mid] < key) lo = mid + 1; else hi = mid;
    }
    return lo;
}

__global__ void pool_out(const float* __restrict__ h, const int* __restrict__ batch,
                         const float* __restrict__ Wout, const float* __restrict__ bout,
                         float* __restrict__ out) {
    __shared__ float smax[4][DIM];
    __shared__ float ssum[4][DIM];
    __shared__ int bounds[2];
    int g = blockIdx.x;
    int tid = threadIdx.x, w = tid >> 6, d = tid & 63;
    if (tid == 0) {
        bounds[0] = lower_bound(batch, N_NODES, g);
        bounds[1] = lower_bound(batch, N_NODES, g + 1);
    }
    __syncthreads();
    int start = bounds[0], end = bounds[1];
    float mx = -INFINITY, sum = 0.0f;
    for (int n = start + w; n < end; n += 4) {
        float v = h[(size_t)n * DIM + d];
        mx = fmaxf(mx, v);
        sum += v;
    }
    smax[w][d] = mx;
    ssum[w][d] = sum;
    __syncthreads();
    if (w == 0) {
        mx = fmaxf(fmaxf(smax[0][d], smax[1][d]), fmaxf(smax[2][d], smax[3][d]));
        sum = ssum[0][d] + ssum[1][d] + ssum[2][d] + ssum[3][d];
        float cnt = (float)(end - start);
        float mean = sum / fmaxf(cnt, 1.0f);
        float v = mx * Wout[d] + mean * Wout[DIM + d];
#pragma unroll
        for (int off = 32; off > 0; off >>= 1) v += __shfl_down(v, off, 64);
        if (d == 0) out[g] = v + bout[0];
    }
}

// ---------------- launch ----------------

static inline size_t align256(size_t x) { return (x + 255) & ~(size_t)255; }

extern "C" void kernel_launch(void* const* d_in, const int* in_sizes, int n_in,
                              void* d_out, int out_size, void* d_ws, size_t ws_size,
                              hipStream_t stream) {
    const float* x     = (const float*)d_in[0];
    const int*   ei    = (const int*)d_in[1];
    const int*   batch = (const int*)d_in[2];
    const float* W0    = (const float*)d_in[3];
    const float* b0    = (const float*)d_in[4];
    const float* W1    = (const float*)d_in[5];
    const float* b1    = (const float*)d_in[6];
    const float* W2    = (const float*)d_in[7];
    const float* b2    = (const float*)d_in[8];
    const float* W3    = (const float*)d_in[9];
    const float* b3    = (const float*)d_in[10];
    const float* Wout  = (const float*)d_in[11];
    const float* bout  = (const float*)d_in[12];
    float* out = (float*)d_out;

    const int* row = ei;            // source
    const int* col = ei + N_EDGES;  // destination

    char* ws = (char*)d_ws;
    size_t off = 0;
    int*    ideg    = (int*)(ws + off);    off += align256((size_t)N_NODES * 4);
    int*    rowtmp  = (int*)(ws + off);    off += align256((size_t)N_NODES * 4);
    int*    rowptr  = (int*)(ws + off);    off += align256(((size_t)N_NODES + 1) * 4);
    int*    cursor  = (int*)(ws + off);    off += align256((size_t)N_NODES * 4);
    int*    bsum    = (int*)(ws + off);    off += align256(256 * 4);
    int*    bsumoff = (int*)(ws + off);    off += align256(256 * 4);
    float*  dinv    = (float*)(ws + off);  off += align256((size_t)N_NODES * 4);
    int2*   ecsr    = (int2*)(ws + off);   off += align256((size_t)N_EDGES * 8);
    __half* hA      = (__half*)(ws + off); off += align256((size_t)N_NODES * DIM * 2);
    __half* hB      = (__half*)(ws + off); off += align256((size_t)N_NODES * DIM * 2);
    float*  hF      = (float*)(ws + off);  off += align256((size_t)N_NODES * DIM * 4);
    (void)ws_size;

    const int node_blocks = (N_NODES + 255) / 256;   // 196
    const int edge_blocks = (N_EDGES + 255) / 256;   // 3125
    const int wave_blocks = N_NODES / 4;             // 12500 (4 waves/block, 1 node/wave)

    // CSR build
    zero_i32<<<node_blocks, 256, 0, stream>>>(ideg, N_NODES);
    deg_count<<<edge_blocks, 256, 0, stream>>>(col, ideg);
    scan_local<<<SCAN_BLOCKS, 256, 0, stream>>>(ideg, rowtmp, bsum);
    scan_block<<<1, 256, 0, stream>>>(bsum, bsumoff);
    scan_final<<<SCAN_BLOCKS, 256, 0, stream>>>(rowtmp, bsumoff, ideg, rowptr, cursor, dinv);
    csr_fill<<<edge_blocks, 256, 0, stream>>>(row, col, dinv, cursor, ecsr);

    // fused layers (fp16 gather buffers; final layer output f32 for pooling)
    layer0_fused<<<wave_blocks, 256, 0, stream>>>(rowptr, ecsr, dinv, x, W0, b0, hA);
    layer64h<__half><<<wave_blocks, 256, 0, stream>>>(rowptr, ecsr, dinv, (const uint2*)hA, W1, b1, hB);
    layer64h<__half><<<wave_blocks, 256, 0, stream>>>(rowptr, ecsr, dinv, (const uint2*)hB, W2, b2, hA);
    layer64h<float><<<wave_blocks, 256, 0, stream>>>(rowptr, ecsr, dinv, (const uint2*)hA, W3, b3, hF);

    // pooling + output
    pool_out<<<N_GRAPHS, 256, 0, stream>>>(hF, batch, Wout, bout, out);
    (void)out_size; (void)n_in; (void)in_sizes;
}